// Round 14
// baseline (23.892 us; speedup 1.0000x reference)
//
#include <hip/hip_runtime.h>

// Polyphase resampler 16000 -> 14400 Hz (SpeedPerturb).
// stride 10, P = 9 phases, W = 14 taps.
// R13 backbone (max-TLP, wave-decoupled, unaligned-float4 direct loads,
// NONTEMPORAL float4 stores) + NONTEMPORAL loads on the interior window
// fetch (read-once input lines marked evict-first in L1/L2; intra-wave
// line reuse is intra-instruction so the hint can't break it).
// Wave owns 64 periods m (outputs 9m..9m+8). out[9m+j] =
// sum_w wav[10m-6+OFF[j]+w]*wgt[14j+w], OFF={0,1,2,3,4,5,6,8,9}.
// M % 64 == 0, TOT == 9*M exactly -> no tails.

#define RS_TPB 256

typedef float float4u __attribute__((ext_vector_type(4), aligned(4)));
typedef float vfloat4 __attribute__((ext_vector_type(4)));  // 16B-aligned native

__global__ __launch_bounds__(RS_TPB) void resample_kernel(
    const float* __restrict__ wav, const float* __restrict__ wgt,
    float* __restrict__ out, int N, int M, int TOT) {
  __shared__ __align__(16) float s_out[4][576];   // per-wave 2304 B

  const int b = blockIdx.y;
  const int tid = threadIdx.x;
  const int w = tid >> 6;
  const int lane = tid & 63;
  const int wbase = blockIdx.x * RS_TPB + (w << 6);  // first period of wave
  if (wbase >= M) return;            // wave-uniform; no block barrier exists

  const int m = wbase + lane;
  const float* __restrict__ wrow = wav + (size_t)b * N;

  // Window: wav[10m-6 .. 10m+17] (24 floats), dword-aligned (in fact 8B).
  const int gbase = 10 * m - 6;
  float win[24];
  if (gbase >= 0 && gbase + 24 <= N) {
#pragma unroll
    for (int r = 0; r < 6; ++r) {
      const float4u v = __builtin_nontemporal_load(
          reinterpret_cast<const float4u*>(wrow + gbase + 4 * r));
      win[4 * r + 0] = v.x;
      win[4 * r + 1] = v.y;
      win[4 * r + 2] = v.z;
      win[4 * r + 3] = v.w;
    }
  } else {
#pragma unroll
    for (int i = 0; i < 24; ++i) {
      const int gi = gbase + i;
      win[i] = (gi >= 0 && gi < N) ? wrow[gi] : 0.0f;
    }
  }

  const int OFF[9] = {0, 1, 2, 3, 4, 5, 6, 8, 9};
#pragma unroll
  for (int j = 0; j < 9; ++j) {
    const float* wp = &wgt[14 * j];
    float acc = 0.0f;
#pragma unroll
    for (int t = 0; t < 14; ++t) acc = fmaf(win[OFF[j] + t], wp[t], acc);
    s_out[w][lane * 9 + j] = acc;   // stride-9 b32: gcd(9,32)=1 -> conflict-free
  }
  __builtin_amdgcn_wave_barrier();  // same-wave order; lgkmcnt by compiler

  // Coalesced NONTEMPORAL float4 store of this wave's 576 contiguous outputs.
  float* __restrict__ orow = out + (size_t)b * TOT + (size_t)wbase * 9;
  const vfloat4* so4 = reinterpret_cast<const vfloat4*>(&s_out[w][0]);
#pragma unroll
  for (int it = 0; it < 3; ++it) {
    const int i4 = it * 64 + lane;
    if (i4 < 144)
      __builtin_nontemporal_store(so4[i4],
                                  reinterpret_cast<vfloat4*>(orow + (i4 << 2)));
  }
}

extern "C" void kernel_launch(void* const* d_in, const int* in_sizes, int n_in,
                              void* d_out, int out_size, void* d_ws, size_t ws_size,
                              hipStream_t stream) {
  const float* wav = (const float*)d_in[0];
  const float* wgt = (const float*)d_in[1];
  float* out = (float*)d_out;

  const int N = 480000;
  const int B = in_sizes[0] / N;   // 16
  const int TOT = out_size / B;    // 432000
  const int M = (TOT + 8) / 9;     // 48000 periods (multiple of 64)

  dim3 grid((M + RS_TPB - 1) / RS_TPB, B);
  resample_kernel<<<grid, RS_TPB, 0, stream>>>(wav, wgt, out, N, M, TOT);
}

// Round 15
// 13.925 us; speedup vs baseline: 1.7158x; 1.7158x over previous
//
#include <hip/hip_runtime.h>

// Polyphase resampler 16000 -> 14400 Hz (SpeedPerturb).
// stride 10, P = 9 phases, W = 14 taps.
// BEST (R13): max-TLP, wave-decoupled, 6 unaligned-float4 direct window
// loads (normal caching — adjacent lanes' windows overlap 2.4x and that
// reuse lives in L1/L2; NT loads proved a 66% regression in R14) +
// NONTEMPORAL float4 output stores (write-once stream: no L2 write-
// allocate, confirmed -1.2us in R13).
// Wave owns 64 periods m (outputs 9m..9m+8). out[9m+j] =
// sum_w wav[10m-6+OFF[j]+w]*wgt[14j+w], OFF={0,1,2,3,4,5,6,8,9}.
// M % 64 == 0, TOT == 9*M exactly -> no tails.

#define RS_TPB 256

typedef float float4u __attribute__((ext_vector_type(4), aligned(4)));
typedef float vfloat4 __attribute__((ext_vector_type(4)));  // 16B-aligned native

__global__ __launch_bounds__(RS_TPB) void resample_kernel(
    const float* __restrict__ wav, const float* __restrict__ wgt,
    float* __restrict__ out, int N, int M, int TOT) {
  __shared__ __align__(16) float s_out[4][576];   // per-wave 2304 B

  const int b = blockIdx.y;
  const int tid = threadIdx.x;
  const int w = tid >> 6;
  const int lane = tid & 63;
  const int wbase = blockIdx.x * RS_TPB + (w << 6);  // first period of wave
  if (wbase >= M) return;            // wave-uniform; no block barrier exists

  const int m = wbase + lane;
  const float* __restrict__ wrow = wav + (size_t)b * N;

  // Window: wav[10m-6 .. 10m+17] (24 floats), dword-aligned (in fact 8B).
  const int gbase = 10 * m - 6;
  float win[24];
  if (gbase >= 0 && gbase + 24 <= N) {
#pragma unroll
    for (int r = 0; r < 6; ++r) {
      const float4u v = *reinterpret_cast<const float4u*>(wrow + gbase + 4 * r);
      win[4 * r + 0] = v.x;
      win[4 * r + 1] = v.y;
      win[4 * r + 2] = v.z;
      win[4 * r + 3] = v.w;
    }
  } else {
#pragma unroll
    for (int i = 0; i < 24; ++i) {
      const int gi = gbase + i;
      win[i] = (gi >= 0 && gi < N) ? wrow[gi] : 0.0f;
    }
  }

  const int OFF[9] = {0, 1, 2, 3, 4, 5, 6, 8, 9};
#pragma unroll
  for (int j = 0; j < 9; ++j) {
    const float* wp = &wgt[14 * j];
    float acc = 0.0f;
#pragma unroll
    for (int t = 0; t < 14; ++t) acc = fmaf(win[OFF[j] + t], wp[t], acc);
    s_out[w][lane * 9 + j] = acc;   // stride-9 b32: gcd(9,32)=1 -> conflict-free
  }
  __builtin_amdgcn_wave_barrier();  // same-wave order; lgkmcnt by compiler

  // Coalesced NONTEMPORAL float4 store of this wave's 576 contiguous outputs.
  float* __restrict__ orow = out + (size_t)b * TOT + (size_t)wbase * 9;
  const vfloat4* so4 = reinterpret_cast<const vfloat4*>(&s_out[w][0]);
#pragma unroll
  for (int it = 0; it < 3; ++it) {
    const int i4 = it * 64 + lane;
    if (i4 < 144)
      __builtin_nontemporal_store(so4[i4],
                                  reinterpret_cast<vfloat4*>(orow + (i4 << 2)));
  }
}

extern "C" void kernel_launch(void* const* d_in, const int* in_sizes, int n_in,
                              void* d_out, int out_size, void* d_ws, size_t ws_size,
                              hipStream_t stream) {
  const float* wav = (const float*)d_in[0];
  const float* wgt = (const float*)d_in[1];
  float* out = (float*)d_out;

  const int N = 480000;
  const int B = in_sizes[0] / N;   // 16
  const int TOT = out_size / B;    // 432000
  const int M = (TOT + 8) / 9;     // 48000 periods (multiple of 64)

  dim3 grid((M + RS_TPB - 1) / RS_TPB, B);
  resample_kernel<<<grid, RS_TPB, 0, stream>>>(wav, wgt, out, N, M, TOT);
}